// Round 4
// baseline (83.331 us; speedup 1.0000x reference)
//
#include <hip/hip_runtime.h>
#include <hip/hip_bf16.h>

// GCN layer: out = D^-1/2 A D^-1/2 (x W^T + b_lin) + bias
// N=8192, E=262144, DI=DO=128. Set-semantics symmetric adjacency as an
// N x N bitmap (8 MB, idempotent atomicOr). Exact degrees counted inline in
// the edge kernel via atomicOr's returned old value. h stored bf16 (halves
// the dominant gather traffic; f32 accumulation everywhere).
//
// Timed-path note: the harness re-poisons d_ws (268 MB, ~42 us) every replay;
// that is outside our control. We optimize our ~26 us share.

#define DIM 128
#define ROWS_PER_BLOCK 16
#define MAXN 1024  // max neighbors per row in LDS (Poisson(64) tail << 1024)

// ---------------- k1: fused zero(bitmap+deg) + linear ------------------------
__global__ __launch_bounds__(256) void setup_kernel(
    const float* __restrict__ x, const float* __restrict__ W,
    const float* __restrict__ b, __hip_bfloat16* __restrict__ hb,
    uint4* __restrict__ zero16, int nLin) {
    const int tid = threadIdx.x;
    if ((int)blockIdx.x >= nLin) {
        // zero bitmap (8 MB) + deg (32 KB): 16 B per thread, exact coverage
        const long long idx = (long long)((int)blockIdx.x - nLin) * 256 + tid;
        zero16[idx] = make_uint4(0u, 0u, 0u, 0u);
        return;
    }
    // linear: h[16 rows, 128] = x @ W^T + b, stored bf16
    __shared__ float xt[ROWS_PER_BLOCK * DIM];
    const int block_row = blockIdx.x * ROWS_PER_BLOCK;
    const float4* xg = reinterpret_cast<const float4*>(x + (long long)block_row * DIM);
    float4* xl = reinterpret_cast<float4*>(xt);
    for (int i = tid; i < ROWS_PER_BLOCK * (DIM / 4); i += 256) xl[i] = xg[i];
    __syncthreads();

    const int d = tid & 127;
    const int half = tid >> 7;
    const float4* W4 = reinterpret_cast<const float4*>(W + (long long)d * DIM);

    float acc[8] = {0.f, 0.f, 0.f, 0.f, 0.f, 0.f, 0.f, 0.f};
    for (int k4 = 0; k4 < DIM / 4; ++k4) {
        const float4 w = W4[k4];
#pragma unroll
        for (int j = 0; j < 8; ++j) {
            const float4 xv =
                reinterpret_cast<const float4*>(xt + (half * 8 + j) * DIM)[k4];
            acc[j] += w.x * xv.x + w.y * xv.y + w.z * xv.z + w.w * xv.w;
        }
    }
    const float bb = b[d];
#pragma unroll
    for (int j = 0; j < 8; ++j) {
        hb[(long long)(block_row + half * 8 + j) * DIM + d] =
            __float2bfloat16(acc[j] + bb);
    }
}

// ---------------- k2: edge scatter + exact set-degree ------------------------
__global__ __launch_bounds__(256) void edge_kernel(
    const int* __restrict__ erow, const int* __restrict__ ecol,
    unsigned int* __restrict__ bitmap, int* __restrict__ deg, int E, int WPR) {
    const int e = blockIdx.x * 256 + threadIdx.x;
    if (e >= E) return;
    const int r = erow[e];
    const int c = ecol[e];
    const unsigned int bc = 1u << (c & 31);
    const unsigned int br = 1u << (r & 31);
    const unsigned int o1 = atomicOr(bitmap + (long long)r * WPR + (c >> 5), bc);
    if (!(o1 & bc)) atomicAdd(deg + r, 1);
    const unsigned int o2 = atomicOr(bitmap + (long long)c * WPR + (r >> 5), br);
    if (!(o2 & br)) atomicAdd(deg + c, 1);
}

// ---------------- k3: aggregate, one block per row ---------------------------
// phase A: bitmap row -> LDS neighbor list + weights rsqrt(deg[j])
// phase B: 16 groups x 16 lanes, uint4 (8 x bf16) gather, 4 loads in flight
__global__ __launch_bounds__(256) void aggregate_kernel(
    const unsigned int* __restrict__ bitmap, const uint4* __restrict__ h16,
    const int* __restrict__ deg, const float* __restrict__ bias,
    float* __restrict__ out, int WPR) {
    __shared__ int nbr[MAXN];
    __shared__ float wgt[MAXN];
    __shared__ int wave_sums[4];
    __shared__ float partial[16 * DIM];

    const int i = blockIdx.x;
    const int tid = threadIdx.x;
    const unsigned int* rowp = bitmap + (long long)i * WPR;

    unsigned int w = (tid < WPR) ? rowp[tid] : 0u;
    const int cnt = __popc(w);

    // block-wide exclusive scan (wave shfl scan + wave offsets)
    const int lane = tid & 63;
    const int wave = tid >> 6;
    int scan = cnt;
#pragma unroll
    for (int off = 1; off < 64; off <<= 1) {
        const int v = __shfl_up(scan, off);
        if (lane >= off) scan += v;
    }
    if (lane == 63) wave_sums[wave] = scan;
    __syncthreads();
    int wave_off = 0;
    for (int k = 0; k < wave; ++k) wave_off += wave_sums[k];
    int base = wave_off + scan - cnt;

    while (w) {
        const int bpos = __ffs(w) - 1;
        w &= w - 1;
        const int j = tid * 32 + bpos;
        if (base < MAXN) {
            nbr[base] = j;
            wgt[base] = rsqrtf((float)deg[j] + 1e-6f);
        }
        ++base;
    }
    __syncthreads();
    int cnt_total = wave_sums[0] + wave_sums[1] + wave_sums[2] + wave_sums[3];
    if (cnt_total > MAXN) cnt_total = MAXN;

    // ---- phase B: lane16 covers channels lane16*8 .. lane16*8+7 ----
    const int lane16 = tid & 15;
    const int g = tid >> 4;  // neighbor group 0..15
    float a0 = 0.f, a1 = 0.f, a2 = 0.f, a3 = 0.f;
    float a4 = 0.f, a5 = 0.f, a6 = 0.f, a7 = 0.f;

#define ACC8(v, wv)                                                      \
    {                                                                    \
        a0 += (wv)*__uint_as_float((v).x << 16);                         \
        a1 += (wv)*__uint_as_float((v).x & 0xffff0000u);                 \
        a2 += (wv)*__uint_as_float((v).y << 16);                         \
        a3 += (wv)*__uint_as_float((v).y & 0xffff0000u);                 \
        a4 += (wv)*__uint_as_float((v).z << 16);                         \
        a5 += (wv)*__uint_as_float((v).z & 0xffff0000u);                 \
        a6 += (wv)*__uint_as_float((v).w << 16);                         \
        a7 += (wv)*__uint_as_float((v).w & 0xffff0000u);                 \
    }

    int m = g;
    for (; m + 48 < cnt_total; m += 64) {
        const int j0 = nbr[m], j1 = nbr[m + 16], j2 = nbr[m + 32], j3 = nbr[m + 48];
        const float w0 = wgt[m], w1 = wgt[m + 16], w2 = wgt[m + 32], w3 = wgt[m + 48];
        const uint4 v0 = h16[(j0 << 4) + lane16];
        const uint4 v1 = h16[(j1 << 4) + lane16];
        const uint4 v2 = h16[(j2 << 4) + lane16];
        const uint4 v3 = h16[(j3 << 4) + lane16];
        ACC8(v0, w0);
        ACC8(v1, w1);
        ACC8(v2, w2);
        ACC8(v3, w3);
    }
    for (; m < cnt_total; m += 16) {
        const int j = nbr[m];
        const float wm = wgt[m];
        const uint4 v = h16[(j << 4) + lane16];
        ACC8(v, wm);
    }
#undef ACC8

    float* p = partial + g * DIM + lane16 * 8;
    p[0] = a0; p[1] = a1; p[2] = a2; p[3] = a3;
    p[4] = a4; p[5] = a5; p[6] = a6; p[7] = a7;
    __syncthreads();

    if (tid < DIM) {
        float s = 0.f;
#pragma unroll
        for (int k = 0; k < 16; ++k) s += partial[k * DIM + tid];
        const float d_i = rsqrtf((float)deg[i] + 1e-6f);
        out[(long long)i * DIM + tid] = s * d_i + bias[tid];
    }
}

extern "C" void kernel_launch(void* const* d_in, const int* in_sizes, int n_in,
                              void* d_out, int out_size, void* d_ws, size_t ws_size,
                              hipStream_t stream) {
    const float* x = (const float*)d_in[0];
    const int* ei = (const int*)d_in[1];  // int32 per harness contract, [2, E]
    const float* W = (const float*)d_in[2];
    const float* b_lin = (const float*)d_in[3];
    const float* bias = (const float*)d_in[4];
    float* out = (float*)d_out;

    const int N = in_sizes[0] / DIM;   // 8192
    const int E = in_sizes[1] / 2;     // 262144
    const int WPR = (N + 31) >> 5;     // 256 words per bitmap row

    unsigned int* bitmap = (unsigned int*)d_ws;
    const long long bitmap_bytes = (long long)N * WPR * 4;          // 8 MB
    int* deg = (int*)((char*)d_ws + bitmap_bytes);                  // 32 KB
    __hip_bfloat16* hb =
        (__hip_bfloat16*)((char*)d_ws + bitmap_bytes + (long long)N * 4);

    const long long zero_bytes = bitmap_bytes + (long long)N * 4;   // bitmap+deg
    const int nLin = N / ROWS_PER_BLOCK;                            // 512
    const int nZero = (int)(zero_bytes / (256 * 16));               // 2056
    setup_kernel<<<nLin + nZero, 256, 0, stream>>>(x, W, b_lin, hb,
                                                   (uint4*)d_ws, nLin);
    edge_kernel<<<(E + 255) / 256, 256, 0, stream>>>(ei, ei + E, bitmap, deg, E,
                                                     WPR);
    aggregate_kernel<<<N, 256, 0, stream>>>(bitmap, (const uint4*)hb, deg, bias,
                                            out, WPR);
}

// Round 5
// 63.443 us; speedup vs baseline: 1.3135x; 1.3135x over previous
//
#include <hip/hip_runtime.h>
#include <hip/hip_bf16.h>

// GCN layer: out = D^-1/2 A D^-1/2 (x W^T + b_lin) + bias
// N=8192, E=262144, DI=DO=128. Set-semantics symmetric adjacency as an
// N x N bitmap (8 MB, fire-and-forget atomicOr — returning atomics cost 6x,
// measured R4). Degrees via popcount pass (exact set semantics). h stored
// bf16 (halves gather traffic; f32 accumulation).
//
// Timed-path note: the harness re-poisons d_ws (268 MB, ~42 us at HBM peak)
// every replay; untouchable. We optimize our ~26 us share.

#define DIM 128
#define ROWS_PER_BLOCK 16
#define MAXN 1024  // max neighbors per row in LDS (Poisson(64) tail << 1024)

// ---------------- k1: fused zero(bitmap) + linear ----------------------------
__global__ __launch_bounds__(256) void setup_kernel(
    const float* __restrict__ x, const float* __restrict__ W,
    const float* __restrict__ b, __hip_bfloat16* __restrict__ hb,
    uint4* __restrict__ zero16, int nLin) {
    const int tid = threadIdx.x;
    if ((int)blockIdx.x >= nLin) {
        // zero bitmap (8 MB): 16 B per thread, exact coverage
        const long long idx = (long long)((int)blockIdx.x - nLin) * 256 + tid;
        zero16[idx] = make_uint4(0u, 0u, 0u, 0u);
        return;
    }
    // linear: h[16 rows, 128] = x @ W^T + b, stored bf16
    __shared__ float xt[ROWS_PER_BLOCK * DIM];
    const int block_row = blockIdx.x * ROWS_PER_BLOCK;
    const float4* xg = reinterpret_cast<const float4*>(x + (long long)block_row * DIM);
    float4* xl = reinterpret_cast<float4*>(xt);
    for (int i = tid; i < ROWS_PER_BLOCK * (DIM / 4); i += 256) xl[i] = xg[i];
    __syncthreads();

    const int d = tid & 127;
    const int half = tid >> 7;
    const float4* W4 = reinterpret_cast<const float4*>(W + (long long)d * DIM);

    float acc[8] = {0.f, 0.f, 0.f, 0.f, 0.f, 0.f, 0.f, 0.f};
    for (int k4 = 0; k4 < DIM / 4; ++k4) {
        const float4 w = W4[k4];
#pragma unroll
        for (int j = 0; j < 8; ++j) {
            const float4 xv =
                reinterpret_cast<const float4*>(xt + (half * 8 + j) * DIM)[k4];
            acc[j] += w.x * xv.x + w.y * xv.y + w.z * xv.z + w.w * xv.w;
        }
    }
    const float bb = b[d];
#pragma unroll
    for (int j = 0; j < 8; ++j) {
        hb[(long long)(block_row + half * 8 + j) * DIM + d] =
            __float2bfloat16(acc[j] + bb);
    }
}

// ---------------- k2: edge scatter (non-returning atomics) -------------------
__global__ __launch_bounds__(256) void edge_kernel(
    const int* __restrict__ erow, const int* __restrict__ ecol,
    unsigned int* __restrict__ bitmap, int E, int WPR) {
    const int e = blockIdx.x * 256 + threadIdx.x;
    if (e >= E) return;
    const int r = erow[e];
    const int c = ecol[e];
    atomicOr(bitmap + (long long)r * WPR + (c >> 5), 1u << (c & 31));
    atomicOr(bitmap + (long long)c * WPR + (r >> 5), 1u << (r & 31));
}

// ---------------- k3: degree -> dinv, 4 rows/block, wave per row -------------
__global__ __launch_bounds__(256) void degree_kernel(
    const unsigned int* __restrict__ bitmap, float* __restrict__ dinv, int WPR) {
    const int i = blockIdx.x * 4 + (threadIdx.x >> 6);
    const int lane = threadIdx.x & 63;
    const uint4* rowp = reinterpret_cast<const uint4*>(bitmap + (long long)i * WPR);
    // WPR=256 words = 64 uint4 -> one uint4 per lane
    const uint4 v = rowp[lane];
    int cnt = __popc(v.x) + __popc(v.y) + __popc(v.z) + __popc(v.w);
#pragma unroll
    for (int off = 32; off > 0; off >>= 1) cnt += __shfl_down(cnt, off);
    if (lane == 0) dinv[i] = rsqrtf((float)cnt + 1e-6f);
}

// ---------------- k4: aggregate, one block per row ---------------------------
// phase A: bitmap row -> LDS neighbor list + weights dinv[j]
// phase B: 16 groups x 16 lanes, uint4 (8 x bf16) gather, 4 loads in flight
__global__ __launch_bounds__(256) void aggregate_kernel(
    const unsigned int* __restrict__ bitmap, const uint4* __restrict__ h16,
    const float* __restrict__ dinv, const float* __restrict__ bias,
    float* __restrict__ out, int WPR) {
    __shared__ int nbr[MAXN];
    __shared__ float wgt[MAXN];
    __shared__ int wave_sums[4];
    __shared__ float partial[16 * DIM];

    const int i = blockIdx.x;
    const int tid = threadIdx.x;
    const float d_i = dinv[i];
    const unsigned int* rowp = bitmap + (long long)i * WPR;

    unsigned int w = (tid < WPR) ? rowp[tid] : 0u;
    const int cnt = __popc(w);

    // block-wide exclusive scan (wave shfl scan + wave offsets)
    const int lane = tid & 63;
    const int wave = tid >> 6;
    int scan = cnt;
#pragma unroll
    for (int off = 1; off < 64; off <<= 1) {
        const int v = __shfl_up(scan, off);
        if (lane >= off) scan += v;
    }
    if (lane == 63) wave_sums[wave] = scan;
    __syncthreads();
    int wave_off = 0;
    for (int k = 0; k < wave; ++k) wave_off += wave_sums[k];
    int base = wave_off + scan - cnt;

    while (w) {
        const int bpos = __ffs(w) - 1;
        w &= w - 1;
        const int j = tid * 32 + bpos;
        if (base < MAXN) {
            nbr[base] = j;
            wgt[base] = dinv[j];
        }
        ++base;
    }
    __syncthreads();
    int cnt_total = wave_sums[0] + wave_sums[1] + wave_sums[2] + wave_sums[3];
    if (cnt_total > MAXN) cnt_total = MAXN;

    // ---- phase B: lane16 covers channels lane16*8 .. lane16*8+7 ----
    const int lane16 = tid & 15;
    const int g = tid >> 4;  // neighbor group 0..15
    float a0 = 0.f, a1 = 0.f, a2 = 0.f, a3 = 0.f;
    float a4 = 0.f, a5 = 0.f, a6 = 0.f, a7 = 0.f;

#define ACC8(v, wv)                                                      \
    {                                                                    \
        a0 += (wv)*__uint_as_float((v).x << 16);                         \
        a1 += (wv)*__uint_as_float((v).x & 0xffff0000u);                 \
        a2 += (wv)*__uint_as_float((v).y << 16);                         \
        a3 += (wv)*__uint_as_float((v).y & 0xffff0000u);                 \
        a4 += (wv)*__uint_as_float((v).z << 16);                         \
        a5 += (wv)*__uint_as_float((v).z & 0xffff0000u);                 \
        a6 += (wv)*__uint_as_float((v).w << 16);                         \
        a7 += (wv)*__uint_as_float((v).w & 0xffff0000u);                 \
    }

    int m = g;
    for (; m + 48 < cnt_total; m += 64) {
        const int j0 = nbr[m], j1 = nbr[m + 16], j2 = nbr[m + 32], j3 = nbr[m + 48];
        const float w0 = wgt[m], w1 = wgt[m + 16], w2 = wgt[m + 32], w3 = wgt[m + 48];
        const uint4 v0 = h16[(j0 << 4) + lane16];
        const uint4 v1 = h16[(j1 << 4) + lane16];
        const uint4 v2 = h16[(j2 << 4) + lane16];
        const uint4 v3 = h16[(j3 << 4) + lane16];
        ACC8(v0, w0);
        ACC8(v1, w1);
        ACC8(v2, w2);
        ACC8(v3, w3);
    }
    for (; m < cnt_total; m += 16) {
        const int j = nbr[m];
        const float wm = wgt[m];
        const uint4 v = h16[(j << 4) + lane16];
        ACC8(v, wm);
    }
#undef ACC8

    float* p = partial + g * DIM + lane16 * 8;
    p[0] = a0; p[1] = a1; p[2] = a2; p[3] = a3;
    p[4] = a4; p[5] = a5; p[6] = a6; p[7] = a7;
    __syncthreads();

    if (tid < DIM) {
        float s = 0.f;
#pragma unroll
        for (int k = 0; k < 16; ++k) s += partial[k * DIM + tid];
        out[(long long)i * DIM + tid] = s * d_i + bias[tid];
    }
}

extern "C" void kernel_launch(void* const* d_in, const int* in_sizes, int n_in,
                              void* d_out, int out_size, void* d_ws, size_t ws_size,
                              hipStream_t stream) {
    const float* x = (const float*)d_in[0];
    const int* ei = (const int*)d_in[1];  // int32 per harness contract, [2, E]
    const float* W = (const float*)d_in[2];
    const float* b_lin = (const float*)d_in[3];
    const float* bias = (const float*)d_in[4];
    float* out = (float*)d_out;

    const int N = in_sizes[0] / DIM;   // 8192
    const int E = in_sizes[1] / 2;     // 262144
    const int WPR = (N + 31) >> 5;     // 256 words per bitmap row

    unsigned int* bitmap = (unsigned int*)d_ws;
    const long long bitmap_bytes = (long long)N * WPR * 4;  // 8 MB
    float* dinv = (float*)((char*)d_ws + bitmap_bytes);     // 32 KB
    __hip_bfloat16* hb =
        (__hip_bfloat16*)((char*)d_ws + bitmap_bytes + (long long)N * 4);

    const int nLin = N / ROWS_PER_BLOCK;                 // 512
    const int nZero = (int)(bitmap_bytes / (256 * 16));  // 2048
    setup_kernel<<<nLin + nZero, 256, 0, stream>>>(x, W, b_lin, hb,
                                                   (uint4*)bitmap, nLin);
    edge_kernel<<<(E + 255) / 256, 256, 0, stream>>>(ei, ei + E, bitmap, E, WPR);
    degree_kernel<<<N / 4, 256, 0, stream>>>(bitmap, dinv, WPR);
    aggregate_kernel<<<N, 256, 0, stream>>>(bitmap, (const uint4*)hb, dinv, bias,
                                            out, WPR);
}